// Round 13
// baseline (1232.818 us; speedup 1.0000x reference)
//
#include <hip/hip_runtime.h>
#include <hip/hip_fp16.h>

// Problem constants (fixed by the reference)
constexpr int kN   = 50000;
constexpr int kE   = 800000;
constexpr float kNEG = 0.2f;
constexpr float kEPS = 1e-5f;
constexpr int kNB16 = kN / 16;   // 3125 blocks of 16 nodes (exact)

__device__ __forceinline__ float lrelu(float x) { return x > 0.f ? x : kNEG * x; }

__device__ __forceinline__ void unpack8(int4 raw, float* t) {
    __half2* h = (__half2*)&raw;
    #pragma unroll
    for (int i = 0; i < 4; ++i) { float2 f = __half22float2(h[i]); t[2*i] = f.x; t[2*i+1] = f.y; }
}

// ---------------- graph build ----------------

__global__ void k_count(const int* __restrict__ ei, int* __restrict__ cnt) {
    int e = blockIdx.x * blockDim.x + threadIdx.x;
    if (e < kE) atomicAdd(&cnt[ei[kE + e]], 1);   // dst = ei[1][e]
}

__global__ void k_scan(const int* __restrict__ cnt, int* __restrict__ rp,
                       float* __restrict__ dinv) {
    __shared__ int wsum[16];
    __shared__ int chunk_base;
    int tid = threadIdx.x, lane = tid & 63, wid = tid >> 6;
    if (tid == 0) chunk_base = 0;
    __syncthreads();
    for (int base = 0; base < kN; base += 1024) {
        int i = base + tid;
        int v = (i < kN) ? cnt[i] : 0;
        if (i < kN) dinv[i] = rsqrtf((float)(v + 1));
        int s = v;
        #pragma unroll
        for (int off = 1; off < 64; off <<= 1) {
            int t = __shfl_up(s, off);
            if (lane >= off) s += t;
        }
        if (lane == 63) wsum[wid] = s;
        __syncthreads();
        if (wid == 0) {
            int t = (lane < 16) ? wsum[lane] : 0;
            #pragma unroll
            for (int off = 1; off < 16; off <<= 1) {
                int u = __shfl_up(t, off);
                if (lane >= off) t += u;
            }
            if (lane < 16) wsum[lane] = t;
        }
        __syncthreads();
        int wbase = (wid > 0) ? wsum[wid - 1] : 0;
        int total = wsum[15];
        int excl = chunk_base + wbase + s - v;
        if (i < kN) rp[i] = excl;
        __syncthreads();
        if (tid == 0) chunk_base += total;
        __syncthreads();
    }
    if (threadIdx.x == 0) rp[kN] = chunk_base;
}

__global__ void k_fill(const int* __restrict__ ei, const int* __restrict__ rp,
                       int* __restrict__ fill, int* __restrict__ col) {
    int e = blockIdx.x * blockDim.x + threadIdx.x;
    if (e < kE) {
        int d = ei[kE + e];
        int pos = rp[d] + atomicAdd(&fill[d], 1);
        col[pos] = ei[e];
    }
}

// ---------------- combo: {agg16(mask)->am} || {bnstats(x)->sraw_x} ----------------

__global__ void k_combo(const float* __restrict__ mask, const float* __restrict__ x,
                        const float* __restrict__ dinv, const int* __restrict__ rp,
                        const int* __restrict__ col,
                        float* __restrict__ am, float* __restrict__ sraw_x) {
    if (blockIdx.x < kNB16) {
        int node = blockIdx.x * 16 + threadIdx.x / 16;
        int f = threadIdx.x % 16;
        float dv = dinv[node];
        float acc = dv * mask[(size_t)node * 16 + f];
        int b = rp[node], e2 = rp[node + 1];
        for (int i = b; i < e2; ++i) {
            int u = col[i];
            acc += dinv[u] * mask[(size_t)u * 16 + f];
        }
        am[(size_t)node * 16 + f] = dv * acc;
    } else {
        int bb = blockIdx.x - kNB16;   // 0..255
        int f = threadIdx.x % 64, r0 = threadIdx.x / 64;
        float s = 0.f, s2 = 0.f;
        for (int v = bb * 4 + r0; v < kN; v += 256 * 4) {
            float val = x[(size_t)v * 64 + f];
            s += val; s2 += val * val;
        }
        __shared__ float sh[256], sh2[256];
        sh[threadIdx.x] = s; sh2[threadIdx.x] = s2;
        __syncthreads();
        if (threadIdx.x < 64) {
            s  = sh[threadIdx.x]  + sh[threadIdx.x + 64]  + sh[threadIdx.x + 128]  + sh[threadIdx.x + 192];
            s2 = sh2[threadIdx.x] + sh2[threadIdx.x + 64] + sh2[threadIdx.x + 128] + sh2[threadIdx.x + 192];
            atomicAdd(&sraw_x[f], s);
            atomicAdd(&sraw_x[64 + f], s2);
        }
    }
}

// ---------------- BN stats over z1 ----------------

__global__ void k_bnstats(const float* __restrict__ x, float* __restrict__ stats) {
    int f = threadIdx.x % 64, r0 = threadIdx.x / 64;
    float s = 0.f, s2 = 0.f;
    for (int v = blockIdx.x * 4 + r0; v < kN; v += gridDim.x * 4) {
        float val = x[(size_t)v * 64 + f];
        s += val; s2 += val * val;
    }
    __shared__ float sh[256], sh2[256];
    sh[threadIdx.x] = s; sh2[threadIdx.x] = s2;
    __syncthreads();
    if (threadIdx.x < 64) {
        s  = sh[threadIdx.x]  + sh[threadIdx.x + 64]  + sh[threadIdx.x + 128]  + sh[threadIdx.x + 192];
        s2 = sh2[threadIdx.x] + sh2[threadIdx.x + 64] + sh2[threadIdx.x + 128] + sh2[threadIdx.x + 192];
        atomicAdd(&stats[f], s);
        atomicAdd(&stats[64 + f], s2);
    }
}

// ---------------- Pall[:, set] = dinv .* relu(am @ w0_set + b0_set), 3 sets ----------------
// Pall layout: [N][384] fp16 (set-major slices of 128).

__global__ void k_mf3(const float* __restrict__ am,
                      const float* __restrict__ w0a, const float* __restrict__ b0a,
                      const float* __restrict__ w0b, const float* __restrict__ b0b,
                      const float* __restrict__ w0c, const float* __restrict__ b0c,
                      const float* __restrict__ dinv, __half* __restrict__ Pall) {
    int set = blockIdx.x / kNB16;            // 0,1,2
    int blk = blockIdx.x - set * kNB16;
    const float* w0 = (set == 0) ? w0a : (set == 1) ? w0b : w0c;
    const float* b0 = (set == 0) ? b0a : (set == 1) ? b0b : b0c;
    __shared__ float w[16 * 128];
    __shared__ float a[16 * 16];
    int tid = threadIdx.x;
    int n0 = blk * 16;
    {
        const float4* w04 = (const float4*)w0;
        float4* w4 = (float4*)w;
        #pragma unroll
        for (int i = 0; i < 2; ++i) w4[tid + 256 * i] = w04[tid + 256 * i];
        if (tid < 64) {
            const float4* am4 = (const float4*)am;
            int node = n0 + tid / 4;
            ((float4*)a)[tid] = am4[(size_t)node * 4 + (tid & 3)];
        }
    }
    __syncthreads();
    int f = tid % 128, g = tid / 128;
    float bf = b0[f];
    for (int j = 0; j < 8; ++j) {
        int nl = g * 8 + j;
        int node = n0 + nl;
        float acc = bf;
        #pragma unroll
        for (int k = 0; k < 16; ++k) acc += a[nl * 16 + k] * w[k * 128 + f];
        Pall[(size_t)node * 384 + set * 128 + f] = __float2half(dinv[node] * fmaxf(acc, 0.f));
    }
}

// ---------------- stage-1 FUSED: tri-layer CSR gather + SPADE(s1) + GAT-in(g1) ----------------
// phase 0: ONE edge traversal gathers all 3 layers' Q:
//   Qa -> LDS tile (consumed by phases 1-2); Qb, Qc -> global fp16 (for stage 2).

__global__ void k_spgat1(const float* __restrict__ xin, const __half* __restrict__ Pall,
                         const float* __restrict__ wg, const float* __restrict__ bg,
                         const float* __restrict__ wb, const float* __restrict__ bb,
                         const float* __restrict__ sraw,
                         const float* __restrict__ W, const float* __restrict__ as_,
                         const float* __restrict__ ad_,
                         __half* __restrict__ h1, float* __restrict__ esed,
                         __half* __restrict__ Qb, __half* __restrict__ Qc,
                         const float* __restrict__ dinv, const int* __restrict__ rp,
                         const int* __restrict__ col) {
    __shared__ float smem[6144];   // 24 KB, phase-aliased
    float* a   = smem;             // [16][128] Qa tile
    float* wgs = smem + 2048;
    float* wbs = smem + 4096;
    float* ys  = smem;
    float* ws  = smem + 1024;
    int tid = threadIdx.x;
    int n0 = blockIdx.x * 16;
    {   // phase 0: tri-gather (16 lanes/node, 3 independent int4 loads per neighbor)
        int node = n0 + tid / 16;
        int l = tid & 15;
        const int4* P4 = (const int4*)Pall;    // row = 48 int4 (a:0-15, b:16-31, c:32-47)
        float dv = dinv[node];
        float aa[8], ab[8], ac[8], t[8];
        unpack8(P4[(size_t)node * 48 + l], aa);
        unpack8(P4[(size_t)node * 48 + 16 + l], ab);
        unpack8(P4[(size_t)node * 48 + 32 + l], ac);
        int b = rp[node], e2 = rp[node + 1];
        for (int base = b; base < e2; base += 16) {
            int idx = base + l;
            int myu = (idx < e2) ? col[idx] : 0;
            int n = min(16, e2 - base);
            for (int cc = 0; cc < n; ++cc) {
                int u = __shfl(myu, cc, 16);
                size_t r0 = (size_t)u * 48 + l;
                int4 ra = P4[r0], rb = P4[r0 + 16], rc = P4[r0 + 32];
                unpack8(ra, t);
                #pragma unroll
                for (int q = 0; q < 8; ++q) aa[q] += t[q];
                unpack8(rb, t);
                #pragma unroll
                for (int q = 0; q < 8; ++q) ab[q] += t[q];
                unpack8(rc, t);
                #pragma unroll
                for (int q = 0; q < 8; ++q) ac[q] += t[q];
            }
        }
        float* dst = a + (tid / 16) * 128 + l * 8;
        ((float4*)dst)[0] = make_float4(dv * aa[0], dv * aa[1], dv * aa[2], dv * aa[3]);
        ((float4*)dst)[1] = make_float4(dv * aa[4], dv * aa[5], dv * aa[6], dv * aa[7]);
        int4 r; __half2* hp = (__half2*)&r;
        #pragma unroll
        for (int i = 0; i < 4; ++i) hp[i] = __floats2half2_rn(dv * ab[2*i], dv * ab[2*i+1]);
        ((int4*)Qb)[(size_t)node * 16 + l] = r;
        #pragma unroll
        for (int i = 0; i < 4; ++i) hp[i] = __floats2half2_rn(dv * ac[2*i], dv * ac[2*i+1]);
        ((int4*)Qc)[(size_t)node * 16 + l] = r;
    }
    int f = tid % 64, nl = tid / 64;
    float accg[4] = {0,0,0,0}, accb[4] = {0,0,0,0};
    const float4* wg4 = (const float4*)wg;
    const float4* wb4 = (const float4*)wb;
    for (int c = 0; c < 4; ++c) {
        __syncthreads();
        {
            float4* wgs4 = (float4*)wgs;
            float4* wbs4 = (float4*)wbs;
            #pragma unroll
            for (int i = 0; i < 2; ++i) {
                int idx = tid + 256 * i;
                wgs4[idx] = wg4[c * 512 + idx];
                wbs4[idx] = wb4[c * 512 + idx];
            }
        }
        __syncthreads();
        #pragma unroll
        for (int kk = 0; kk < 32; ++kk) {
            float wgk = wgs[kk * 64 + f], wbk = wbs[kk * 64 + f];
            int k = c * 32 + kk;
            #pragma unroll
            for (int j = 0; j < 4; ++j) {
                float av = a[(j * 4 + nl) * 128 + k];
                accg[j] += av * wgk;
                accb[j] += av * wbk;
            }
        }
    }
    float mu, rstd;
    {
        float s = sraw[f], s2 = sraw[64 + f];
        mu = s * (1.f / kN);
        rstd = rsqrtf(s2 * (1.f / kN) - mu * mu + kEPS);
    }
    float bgf = bg[f], bbf = bb[f];
    float yv[4];
    #pragma unroll
    for (int j = 0; j < 4; ++j) {
        int node = n0 + j * 4 + nl;
        float xv = xin[(size_t)node * 64 + f];
        float g = accg[j] + bgf, b = accb[j] + bbf;
        yv[j] = lrelu((xv - mu) * rstd * (1.f + g) + b);
    }
    __syncthreads();
    #pragma unroll
    for (int j = 0; j < 4; ++j) ys[(j * 4 + nl) * 64 + f] = yv[j];
    {
        const float4* W4 = (const float4*)W;
        float4* ws4 = (float4*)ws;
        #pragma unroll
        for (int i = 0; i < 4; ++i) ws4[tid + 256 * i] = W4[tid + 256 * i];
    }
    __syncthreads();
    float asf = as_[f], adf = ad_[f];
    float acc[4] = {0,0,0,0};
    for (int k = 0; k < 64; ++k) {
        float w = ws[k * 64 + f];
        #pragma unroll
        for (int j = 0; j < 4; ++j) acc[j] += ys[(j * 4 + nl) * 64 + k] * w;
    }
    #pragma unroll
    for (int j = 0; j < 4; ++j) {
        int node = n0 + j * 4 + nl;
        float hv = acc[j];
        float es = hv * asf, ed = hv * adf;
        #pragma unroll
        for (int off = 1; off < 16; off <<= 1) {
            es += __shfl_xor(es, off);
            ed += __shfl_xor(ed, off);
        }
        h1[(size_t)node * 64 + f] = __float2half(hv);
        if ((f & 15) == 0) {
            int hh = f >> 4;
            esed[node * 16 + hh] = es;
            esed[node * 16 + 4 + hh] = ed;
        }
    }
}

// ---------------- stage-2 FUSED SPADE+GAT-in (pre-gathered Q, A/B split) ----------------
// h written INTERLEAVED into h_all[N][128]: A -> even halves, B -> odd halves.

struct Sp2Args {
    const float* xin; const __half* Q;
    const float *wg, *bg, *wb, *bb, *sraw, *W, *as_, *ad_;
    int eslot, hoff;
};

__global__ void k_spgat2(Sp2Args A, Sp2Args B, __half* __restrict__ hall,
                         float* __restrict__ esed) {
    Sp2Args G = (blockIdx.x < kNB16) ? A : B;
    int blk = (blockIdx.x < kNB16) ? blockIdx.x : blockIdx.x - kNB16;
    __shared__ float smem[6144];
    float* a   = smem;
    float* wgs = smem + 2048;
    float* wbs = smem + 4096;
    float* ys  = smem;
    float* ws  = smem + 1024;
    int tid = threadIdx.x;
    int n0 = blk * 16;
    {   // stage Q tile (fp16 coalesced -> f32 LDS)
        const int4* q4 = (const int4*)G.Q;
        int node = n0 + tid / 16, h8 = tid & 15;
        float t[8];
        unpack8(q4[(size_t)node * 16 + h8], t);
        float* dst = a + (tid / 16) * 128 + h8 * 8;
        ((float4*)dst)[0] = make_float4(t[0], t[1], t[2], t[3]);
        ((float4*)dst)[1] = make_float4(t[4], t[5], t[6], t[7]);
    }
    int f = tid % 64, nl = tid / 64;
    float accg[4] = {0,0,0,0}, accb[4] = {0,0,0,0};
    const float4* wg4 = (const float4*)G.wg;
    const float4* wb4 = (const float4*)G.wb;
    for (int c = 0; c < 4; ++c) {
        __syncthreads();
        {
            float4* wgs4 = (float4*)wgs;
            float4* wbs4 = (float4*)wbs;
            #pragma unroll
            for (int i = 0; i < 2; ++i) {
                int idx = tid + 256 * i;
                wgs4[idx] = wg4[c * 512 + idx];
                wbs4[idx] = wb4[c * 512 + idx];
            }
        }
        __syncthreads();
        #pragma unroll
        for (int kk = 0; kk < 32; ++kk) {
            float wgk = wgs[kk * 64 + f], wbk = wbs[kk * 64 + f];
            int k = c * 32 + kk;
            #pragma unroll
            for (int j = 0; j < 4; ++j) {
                float av = a[(j * 4 + nl) * 128 + k];
                accg[j] += av * wgk;
                accb[j] += av * wbk;
            }
        }
    }
    float mu, rstd;
    {
        float s = G.sraw[f], s2 = G.sraw[64 + f];
        mu = s * (1.f / kN);
        rstd = rsqrtf(s2 * (1.f / kN) - mu * mu + kEPS);
    }
    float bgf = G.bg[f], bbf = G.bb[f];
    float yv[4];
    #pragma unroll
    for (int j = 0; j < 4; ++j) {
        int node = n0 + j * 4 + nl;
        float xv = G.xin[(size_t)node * 64 + f];
        float g = accg[j] + bgf, b = accb[j] + bbf;
        yv[j] = lrelu((xv - mu) * rstd * (1.f + g) + b);
    }
    __syncthreads();
    #pragma unroll
    for (int j = 0; j < 4; ++j) ys[(j * 4 + nl) * 64 + f] = yv[j];
    {
        const float4* W4 = (const float4*)G.W;
        float4* ws4 = (float4*)ws;
        #pragma unroll
        for (int i = 0; i < 4; ++i) ws4[tid + 256 * i] = W4[tid + 256 * i];
    }
    __syncthreads();
    float asf = G.as_[f], adf = G.ad_[f];
    float acc[4] = {0,0,0,0};
    for (int k = 0; k < 64; ++k) {
        float w = ws[k * 64 + f];
        #pragma unroll
        for (int j = 0; j < 4; ++j) acc[j] += ys[(j * 4 + nl) * 64 + k] * w;
    }
    #pragma unroll
    for (int j = 0; j < 4; ++j) {
        int node = n0 + j * 4 + nl;
        float hv = acc[j];
        float es = hv * asf, ed = hv * adf;
        #pragma unroll
        for (int off = 1; off < 16; off <<= 1) {
            es += __shfl_xor(es, off);
            ed += __shfl_xor(ed, off);
        }
        hall[(size_t)node * 128 + 2 * f + G.hoff] = __float2half(hv);
        if ((f & 15) == 0) {
            int hh = f >> 4;
            esed[node * 16 + G.eslot + hh] = es;
            esed[node * 16 + G.eslot + 4 + hh] = ed;
        }
    }
}

// ---------------- GAT aggregate (g1): online softmax -> z1 (f32) ----------------

__global__ void k_gatagg1(const __half* __restrict__ h, const float* __restrict__ esed,
                          const int* __restrict__ rp, const int* __restrict__ col,
                          const float* __restrict__ bias, float* __restrict__ out) {
    int node = blockIdx.x * 4 + threadIdx.x / 64;
    int lane = threadIdx.x & 63;
    int hh = lane >> 4;
    float edv = esed[node * 16 + 4 + hh];
    float m = lrelu(esed[node * 16 + hh] + edv);
    float d = 1.f;
    float acc = __half2float(h[(size_t)node * 64 + lane]);
    int b = rp[node], e2 = rp[node + 1];
    for (int base = b; base < e2; base += 64) {
        int idx = base + lane;
        int myu = (idx < e2) ? col[idx] : 0;
        int n = min(64, e2 - base);
        for (int cc = 0; cc < n; ++cc) {
            int u = __shfl(myu, cc);
            float e = lrelu(esed[u * 16 + hh] + edv);
            float hu = __half2float(h[(size_t)u * 64 + lane]);
            if (e <= m) {
                float p = __expf(e - m);
                d += p; acc += p * hu;
            } else {
                float s = __expf(m - e);
                d = d * s + 1.f; acc = acc * s + hu; m = e;
            }
        }
    }
    out[(size_t)node * 64 + lane] = acc / d + bias[lane];
}

// ---------------- FUSED GAT aggregate g2 + gk + add (interleaved h_all) ----------------

__global__ void k_gatagg2(const __half* __restrict__ hall, const float* __restrict__ esed,
                          const int* __restrict__ rp, const int* __restrict__ col,
                          const float* __restrict__ b2, const float* __restrict__ bk,
                          float* __restrict__ out) {
    int node = blockIdx.x * 4 + threadIdx.x / 64;
    int lane = threadIdx.x & 63;
    int hh = lane >> 4;
    const __half2* h2all = (const __half2*)hall;   // [N][64] __half2 (lo=g2, hi=gk)
    float ed2 = esed[node * 16 + 4 + hh];
    float edk = esed[node * 16 + 12 + hh];
    float m2 = lrelu(esed[node * 16 + hh] + ed2);
    float mk = lrelu(esed[node * 16 + 8 + hh] + edk);
    float d2 = 1.f, dk = 1.f;
    float2 hv0 = __half22float2(h2all[(size_t)node * 64 + lane]);
    float a2 = hv0.x, ak = hv0.y;
    int b = rp[node], e2 = rp[node + 1];
    for (int base = b; base < e2; base += 64) {
        int idx = base + lane;
        int myu = (idx < e2) ? col[idx] : 0;
        int n = min(64, e2 - base);
        for (int cc = 0; cc < n; ++cc) {
            int u = __shfl(myu, cc);
            float q2 = lrelu(esed[u * 16 + hh] + ed2);
            float qk = lrelu(esed[u * 16 + 8 + hh] + edk);
            float2 hv = __half22float2(h2all[(size_t)u * 64 + lane]);
            if (q2 <= m2) { float p = __expf(q2 - m2); d2 += p; a2 += p * hv.x; }
            else { float s = __expf(m2 - q2); d2 = d2 * s + 1.f; a2 = a2 * s + hv.x; m2 = q2; }
            if (qk <= mk) { float p = __expf(qk - mk); dk += p; ak += p * hv.y; }
            else { float s = __expf(mk - qk); dk = dk * s + 1.f; ak = ak * s + hv.y; mk = qk; }
        }
    }
    out[(size_t)node * 64 + lane] = a2 / d2 + b2[lane] + ak / dk + bk[lane];
}

// ---------------- host ----------------

extern "C" void kernel_launch(void* const* d_in, const int* in_sizes, int n_in,
                              void* d_out, int out_size, void* d_ws, size_t ws_size,
                              hipStream_t stream) {
    const float* x    = (const float*)d_in[0];
    const float* mask = (const float*)d_in[1];
    const int*   ei   = (const int*)d_in[2];
    const float* s_w0[3] = {(const float*)d_in[3],  (const float*)d_in[9],  (const float*)d_in[15]};
    const float* s_b0[3] = {(const float*)d_in[4],  (const float*)d_in[10], (const float*)d_in[16]};
    const float* s_wg[3] = {(const float*)d_in[5],  (const float*)d_in[11], (const float*)d_in[17]};
    const float* s_bg[3] = {(const float*)d_in[6],  (const float*)d_in[12], (const float*)d_in[18]};
    const float* s_wb[3] = {(const float*)d_in[7],  (const float*)d_in[13], (const float*)d_in[19]};
    const float* s_bb[3] = {(const float*)d_in[8],  (const float*)d_in[14], (const float*)d_in[20]};
    const float* g_w[3]  = {(const float*)d_in[21], (const float*)d_in[25], (const float*)d_in[29]};
    const float* g_b[3]  = {(const float*)d_in[22], (const float*)d_in[26], (const float*)d_in[30]};
    const float* g_as[3] = {(const float*)d_in[23], (const float*)d_in[27], (const float*)d_in[31]};
    const float* g_ad[3] = {(const float*)d_in[24], (const float*)d_in[28], (const float*)d_in[32]};

    char* base = (char*)d_ws;
    size_t off = 0;
    auto alloc = [&](size_t bytes) -> void* {
        void* p = base + off;
        off = (off + bytes + 255) & ~(size_t)255;
        return p;
    };
    // zero-init region (ONE memset): cnt, fill, sraw_x, sraw_z — contiguous
    int*   cnt    = (int*)alloc((size_t)kN * 4);
    int*   fill   = (int*)alloc((size_t)kN * 4);
    float* sraw_x = (float*)alloc(128 * 4);
    float* sraw_z = (float*)alloc(128 * 4);
    size_t zero_span = off;
    int*    rp    = (int*)alloc((size_t)(kN + 1) * 4);
    int*    col   = (int*)alloc((size_t)kE * 4);
    float*  dinv  = (float*)alloc((size_t)kN * 4);
    float*  am    = (float*)alloc((size_t)kN * 16 * 4);
    __half* Pall  = (__half*)alloc((size_t)kN * 384 * 2);
    __half* Qb    = (__half*)alloc((size_t)kN * 128 * 2);
    __half* Qc    = (__half*)alloc((size_t)kN * 128 * 2);
    __half* h1    = (__half*)alloc((size_t)kN * 64 * 2);
    __half* hall  = (__half*)alloc((size_t)kN * 128 * 2);
    float*  esed  = (float*)alloc((size_t)kN * 16 * 4);
    float*  z1    = (float*)alloc((size_t)kN * 64 * 4);
    (void)ws_size; (void)n_in; (void)in_sizes; (void)out_size;

    const int EB = (kE + 255) / 256;
    const int GB4 = kN / 4;   // 12500

    hipMemsetAsync(cnt, 0, zero_span, stream);
    k_count<<<EB, 256, 0, stream>>>(ei, cnt);
    k_scan<<<1, 1024, 0, stream>>>(cnt, rp, dinv);
    k_fill<<<EB, 256, 0, stream>>>(ei, rp, fill, col);
    k_combo<<<kNB16 + 256, 256, 0, stream>>>(mask, x, dinv, rp, col, am, sraw_x);

    // all three mask-feature MLPs upfront (depend only on am)
    k_mf3<<<3 * kNB16, 256, 0, stream>>>(am, s_w0[0], s_b0[0], s_w0[1], s_b0[1],
                                         s_w0[2], s_b0[2], dinv, Pall);

    // stage 1: tri-gather + SPADE(s1) + GAT-in(g1); materializes Qb, Qc
    k_spgat1<<<kNB16, 256, 0, stream>>>(x, Pall, s_wg[0], s_bg[0], s_wb[0], s_bb[0], sraw_x,
                                        g_w[0], g_as[0], g_ad[0], h1, esed, Qb, Qc,
                                        dinv, rp, col);
    k_gatagg1<<<GB4, 256, 0, stream>>>(h1, esed, rp, col, g_b[0], z1);

    // stage 2
    k_bnstats<<<256, 256, 0, stream>>>(z1, sraw_z);
    {
        Sp2Args A{z1, Qb, s_wg[1], s_bg[1], s_wb[1], s_bb[1], sraw_z,
                  g_w[1], g_as[1], g_ad[1], 0, 0};
        Sp2Args B{x,  Qc, s_wg[2], s_bg[2], s_wb[2], s_bb[2], sraw_x,
                  g_w[2], g_as[2], g_ad[2], 8, 1};
        k_spgat2<<<2 * kNB16, 256, 0, stream>>>(A, B, hall, esed);
    }
    k_gatagg2<<<GB4, 256, 0, stream>>>(hall, esed, rp, col, g_b[1], g_b[2], (float*)d_out);
}